// Round 1
// baseline (365.478 us; speedup 1.0000x reference)
//
#include <hip/hip_runtime.h>
#include <stdint.h>

#define NN 6144        // nodes
#define NC 576         // padded V columns (517 used)

typedef __bf16 bf16x8 __attribute__((ext_vector_type(8)));
typedef float  f32x4  __attribute__((ext_vector_type(4)));

__device__ __forceinline__ unsigned short f2bf(float f) {
  unsigned u = __float_as_uint(f);
  u += 0x7FFFu + ((u >> 16) & 1u);   // RNE
  return (unsigned short)(u >> 16);
}

__device__ __forceinline__ void async_load16(const void* g, void* l) {
  __builtin_amdgcn_global_load_lds(
      (__attribute__((address_space(1))) void*)(uintptr_t)g,
      (__attribute__((address_space(3))) void*)(uint32_t)(uintptr_t)l,
      16, 0, 0);
}

// ---------------- Kernel 1: features, scores-exponentials, V (bf16, col-major), T ----------------
// grid 192 blocks x 256 thr; block handles 32 nodes.
__global__ __launch_bounds__(256) void k1_feat(
    const float* __restrict__ x, const float* __restrict__ W,
    const float* __restrict__ Wb, const float* __restrict__ Aw,
    const float* __restrict__ Ab, unsigned short* __restrict__ Vcm,
    float* __restrict__ e_src, float* __restrict__ T)
{
  __shared__ float xs[256][32];     // xs[k][n], transposed x tile
  __shared__ float hl[32][257];     // h per node (padded +1)
  __shared__ float sdste[4][32];    // exp(s_dst) per head/node
  const int t  = threadIdx.x;
  const int nb = blockIdx.x * 32;

  { // stage x (coalesced read, transposed LDS write)
    const int n = t >> 3, kq = (t & 7) * 32;
    const float4* xp = (const float4*)(x + (size_t)(nb + n) * 256 + kq);
#pragma unroll
    for (int j = 0; j < 8; ++j) {
      float4 v = xp[j];
      int k = kq + j * 4;
      xs[k][n] = v.x; xs[k+1][n] = v.y; xs[k+2][n] = v.z; xs[k+3][n] = v.w;
    }
  }
  __syncthreads();

  const int cg = t & 31, ng = t >> 5;      // 8 cols x 4 nodes per thread
  const int c0 = cg * 8, h = c0 >> 6, d0 = c0 & 63;
  const float* wp = W + h * 16384 + d0;    // W[h][k][d], k stride 64
  float acc[4][8];
#pragma unroll
  for (int i = 0; i < 4; ++i)
#pragma unroll
    for (int j = 0; j < 8; ++j) acc[i][j] = 0.f;

#pragma unroll 4
  for (int k = 0; k < 256; ++k) {
    float4 wa = *(const float4*)(wp + (size_t)k * 64);
    float4 wb = *(const float4*)(wp + (size_t)k * 64 + 4);
    float4 xa = *(const float4*)(&xs[k][ng * 4]);
    float xr[4] = {xa.x, xa.y, xa.z, xa.w};
    float wr[8] = {wa.x, wa.y, wa.z, wa.w, wb.x, wb.y, wb.z, wb.w};
#pragma unroll
    for (int i = 0; i < 4; ++i)
#pragma unroll
      for (int j = 0; j < 8; ++j) acc[i][j] += xr[i] * wr[j];
  }
#pragma unroll
  for (int i = 0; i < 4; ++i)
#pragma unroll
    for (int j = 0; j < 8; ++j)
      hl[ng * 4 + i][c0 + j] = acc[i][j] + Wb[c0 + j];
  __syncthreads();

  if (t < 128) { // (node, head) attention dots
    const int node = t & 31, hd = t >> 5;
    float ss = Ab[hd], sd = 0.f;
#pragma unroll 8
    for (int d = 0; d < 64; ++d) {
      float hv = hl[node][hd * 64 + d];
      ss += hv * Aw[hd * 128 + d];
      sd += hv * Aw[hd * 128 + 64 + d];
    }
    e_src[hd * NN + nb + node] = expf(ss);
    sdste[hd][node] = expf(sd);
  }
  { // T partial (col t)
    float s = 0.f;
#pragma unroll 8
    for (int n2 = 0; n2 < 32; ++n2) s += hl[n2][t];
    atomicAdd(&T[t], s);
  }
  __syncthreads();

  { // write V column-major bf16: lanes sweep nodes -> coalesced
    const int n = t & 31, q = t >> 5;  // 8 groups x 72 cols = 576
    for (int cc = 0; cc < 72; ++cc) {
      int col = q * 72 + cc;
      float val;
      if (col < 512) {
        int hh = col >> 7, rem = col & 127, d = rem & 63;
        float hv = hl[n][hh * 64 + d];
        val = (rem < 64) ? sdste[hh][n] * hv : hv;
      } else if (col < 516) val = sdste[col - 512][n];
      else if (col == 516)  val = 1.0f;
      else                  val = 0.0f;
      Vcm[(size_t)col * NN + nb + n] = f2bf(val);
    }
  }
}

// ---------------- Kernel 2: out2[ks] = adj(0/1 as bf16) @ V  (MFMA) ----------------
// grid 576: cb(3) x ks(2) x rb(96); block tile 64x192, BK=64, 4 waves 2x2.
__global__ __launch_bounds__(256, 3) void k2_gemm(
    const int* __restrict__ adj, const unsigned short* __restrict__ Vcm,
    float* __restrict__ out2)
{
  __shared__ unsigned short lA[64 * 80];   // 64 rows x 64k, stride 80 (pad)
  __shared__ unsigned short lB[192 * 64];  // 192 cols x 64k, XOR-swizzled granules
  const int t  = threadIdx.x;
  const int bid = blockIdx.x;
  const int cb = bid % 3;
  const int ks = (bid / 3) & 1;
  const int rb = bid / 6;
  const int i0 = rb * 64, n0 = cb * 192, k0 = ks * 3072;
  const int w = t >> 6, l = t & 63;
  const int wm = w & 1, wn = w >> 1;
  const int lm = l & 15, lk = l >> 4;
  const int r = t >> 2, cq = t & 3;       // A staging: row, 16-int group
  const int4* adj4 = (const int4*)adj;

  f32x4 acc[2][6];
#pragma unroll
  for (int mt = 0; mt < 2; ++mt)
#pragma unroll
    for (int nt = 0; nt < 6; ++nt) acc[mt][nt] = (f32x4){0.f, 0.f, 0.f, 0.f};

  for (int it = 0; it < 48; ++it) {
    const int kb = k0 + it * 64;
    { // A: 64x64 int32 -> bf16 0/1 into LDS
      size_t base = ((size_t)(i0 + r) * NN + kb + cq * 16) >> 2;
      int4 q0 = adj4[base + 0], q1 = adj4[base + 1];
      int4 q2 = adj4[base + 2], q3 = adj4[base + 3];
      uint4 p0, p1;
      p0.x = (unsigned)q0.x * 0x3F80u | (unsigned)q0.y * 0x3F800000u;
      p0.y = (unsigned)q0.z * 0x3F80u | (unsigned)q0.w * 0x3F800000u;
      p0.z = (unsigned)q1.x * 0x3F80u | (unsigned)q1.y * 0x3F800000u;
      p0.w = (unsigned)q1.z * 0x3F80u | (unsigned)q1.w * 0x3F800000u;
      p1.x = (unsigned)q2.x * 0x3F80u | (unsigned)q2.y * 0x3F800000u;
      p1.y = (unsigned)q2.z * 0x3F80u | (unsigned)q2.w * 0x3F800000u;
      p1.z = (unsigned)q3.x * 0x3F80u | (unsigned)q3.y * 0x3F800000u;
      p1.w = (unsigned)q3.z * 0x3F80u | (unsigned)q3.w * 0x3F800000u;
      *(uint4*)(&lA[r * 80 + cq * 16])     = p0;
      *(uint4*)(&lA[r * 80 + cq * 16 + 8]) = p1;
    }
    { // B: async global->LDS, 16B/lane, XOR-swizzled granules
      const int clbase = w * 48;
      const int crow = l >> 3, j = l & 7;
#pragma unroll
      for (int u = 0; u < 6; ++u) {
        int cl = clbase + u * 8 + crow;
        int g = j ^ (cl & 7);
        const unsigned short* gp = Vcm + (size_t)(n0 + cl) * NN + kb + g * 8;
        async_load16(gp, (char*)lB + (size_t)(clbase + u * 8) * 128);
      }
    }
    __syncthreads();
#pragma unroll
    for (int ks2 = 0; ks2 < 2; ++ks2) {
      const int kgo = ks2 * 4 + lk;
      bf16x8 a0 = *(const bf16x8*)(&lA[(wm * 32 + lm) * 80 + kgo * 8]);
      bf16x8 a1 = *(const bf16x8*)(&lA[(wm * 32 + 16 + lm) * 80 + kgo * 8]);
      const int slot = (kgo ^ (lm & 7)) * 8;
#pragma unroll
      for (int nt = 0; nt < 6; ++nt) {
        bf16x8 b = *(const bf16x8*)(&lB[(wn * 96 + nt * 16 + lm) * 64 + slot]);
        acc[0][nt] = __builtin_amdgcn_mfma_f32_16x16x32_bf16(a0, b, acc[0][nt], 0, 0, 0);
        acc[1][nt] = __builtin_amdgcn_mfma_f32_16x16x32_bf16(a1, b, acc[1][nt], 0, 0, 0);
      }
    }
    __syncthreads();
  }

  float* o = out2 + (size_t)ks * ((size_t)NN * NC);
  const int row0 = i0 + wm * 32 + (l >> 4) * 4;
  const int colb = n0 + wn * 96 + (l & 15);
#pragma unroll
  for (int mt = 0; mt < 2; ++mt)
#pragma unroll
    for (int nt = 0; nt < 6; ++nt)
#pragma unroll
      for (int rr = 0; rr < 4; ++rr)
        o[(size_t)(row0 + mt * 16 + rr) * NC + colb + nt * 16] = acc[mt][nt][rr];
}

// ---------------- Kernel 3: combine ----------------
__global__ __launch_bounds__(256) void k3_final(
    const float* __restrict__ out2, const float* __restrict__ e_src,
    const float* __restrict__ T, float* __restrict__ out)
{
  const int n = blockIdx.x, c = threadIdx.x;
  const int h = c >> 6, d = c & 63;
  const float* ra = out2 + (size_t)n * NC;
  const float* rb = ra + (size_t)NN * NC;
  float Se = ra[h * 128 + d]      + rb[h * 128 + d];
  float Sp = ra[h * 128 + 64 + d] + rb[h * 128 + 64 + d];
  float E  = ra[512 + h] + rb[512 + h];
  float dg = ra[516]     + rb[516];
  float e  = e_src[h * NN + n];
  float D  = e * E + ((float)NN - dg);
  out[(size_t)n * 256 + c] = (e * Se + (T[c] - Sp)) / D;
}

extern "C" void kernel_launch(void* const* d_in, const int* in_sizes, int n_in,
                              void* d_out, int out_size, void* d_ws, size_t ws_size,
                              hipStream_t stream) {
  const float* x  = (const float*)d_in[0];
  const int*   adj= (const int*)d_in[1];
  const float* W  = (const float*)d_in[2];
  const float* Wb = (const float*)d_in[3];
  const float* Aw = (const float*)d_in[4];
  const float* Ab = (const float*)d_in[5];
  float* out = (float*)d_out;
  char* ws = (char*)d_ws;
  unsigned short* Vcm = (unsigned short*)ws;            // 7,077,888 B
  float* e_src = (float*)(ws + 7077888);                // 98,304 B
  float* T     = (float*)(ws + 7176192);                // 1,024 B
  float* out2  = (float*)(ws + 7177216);                // 2 x 6144 x 576 f32

  hipMemsetAsync(T, 0, 1024, stream);
  hipLaunchKernelGGL(k1_feat, dim3(192), dim3(256), 0, stream, x, W, Wb, Aw, Ab, Vcm, e_src, T);
  hipLaunchKernelGGL(k2_gemm, dim3(576), dim3(256), 0, stream, adj, Vcm, out2);
  hipLaunchKernelGGL(k3_final, dim3(NN), dim3(256), 0, stream, out2, e_src, T, out);
}

// Round 2
// 359.923 us; speedup vs baseline: 1.0154x; 1.0154x over previous
//
#include <hip/hip_runtime.h>
#include <stdint.h>

#define NN 6144        // nodes
#define NC 576         // padded V columns (517 used)

typedef __bf16 bf16x8 __attribute__((ext_vector_type(8)));
typedef float  f32x4  __attribute__((ext_vector_type(4)));

__device__ __forceinline__ unsigned short f2bf(float f) {
  unsigned u = __float_as_uint(f);
  u += 0x7FFFu + ((u >> 16) & 1u);   // RNE
  return (unsigned short)(u >> 16);
}

__device__ __forceinline__ void async_load16(const void* g, void* l) {
  __builtin_amdgcn_global_load_lds(
      (__attribute__((address_space(1))) void*)(uintptr_t)g,
      (__attribute__((address_space(3))) void*)(uint32_t)(uintptr_t)l,
      16, 0, 0);
}

// ---------------- Kernel 1: features, scores-exponentials, V (bf16, col-major), T ----------------
// grid 192 blocks x 256 thr; block handles 32 nodes. (unchanged from R1 — passed)
__global__ __launch_bounds__(256) void k1_feat(
    const float* __restrict__ x, const float* __restrict__ W,
    const float* __restrict__ Wb, const float* __restrict__ Aw,
    const float* __restrict__ Ab, unsigned short* __restrict__ Vcm,
    float* __restrict__ e_src, float* __restrict__ T)
{
  __shared__ float xs[256][32];     // xs[k][n], transposed x tile
  __shared__ float hl[32][257];     // h per node (padded +1)
  __shared__ float sdste[4][32];    // exp(s_dst) per head/node
  const int t  = threadIdx.x;
  const int nb = blockIdx.x * 32;

  { // stage x (coalesced read, transposed LDS write)
    const int n = t >> 3, kq = (t & 7) * 32;
    const float4* xp = (const float4*)(x + (size_t)(nb + n) * 256 + kq);
#pragma unroll
    for (int j = 0; j < 8; ++j) {
      float4 v = xp[j];
      int k = kq + j * 4;
      xs[k][n] = v.x; xs[k+1][n] = v.y; xs[k+2][n] = v.z; xs[k+3][n] = v.w;
    }
  }
  __syncthreads();

  const int cg = t & 31, ng = t >> 5;      // 8 cols x 4 nodes per thread
  const int c0 = cg * 8, h = c0 >> 6, d0 = c0 & 63;
  const float* wp = W + h * 16384 + d0;    // W[h][k][d], k stride 64
  float acc[4][8];
#pragma unroll
  for (int i = 0; i < 4; ++i)
#pragma unroll
    for (int j = 0; j < 8; ++j) acc[i][j] = 0.f;

#pragma unroll 4
  for (int k = 0; k < 256; ++k) {
    float4 wa = *(const float4*)(wp + (size_t)k * 64);
    float4 wb = *(const float4*)(wp + (size_t)k * 64 + 4);
    float4 xa = *(const float4*)(&xs[k][ng * 4]);
    float xr[4] = {xa.x, xa.y, xa.z, xa.w};
    float wr[8] = {wa.x, wa.y, wa.z, wa.w, wb.x, wb.y, wb.z, wb.w};
#pragma unroll
    for (int i = 0; i < 4; ++i)
#pragma unroll
      for (int j = 0; j < 8; ++j) acc[i][j] += xr[i] * wr[j];
  }
#pragma unroll
  for (int i = 0; i < 4; ++i)
#pragma unroll
    for (int j = 0; j < 8; ++j)
      hl[ng * 4 + i][c0 + j] = acc[i][j] + Wb[c0 + j];
  __syncthreads();

  if (t < 128) { // (node, head) attention dots
    const int node = t & 31, hd = t >> 5;
    float ss = Ab[hd], sd = 0.f;
#pragma unroll 8
    for (int d = 0; d < 64; ++d) {
      float hv = hl[node][hd * 64 + d];
      ss += hv * Aw[hd * 128 + d];
      sd += hv * Aw[hd * 128 + 64 + d];
    }
    e_src[hd * NN + nb + node] = expf(ss);
    sdste[hd][node] = expf(sd);
  }
  { // T partial (col t)
    float s = 0.f;
#pragma unroll 8
    for (int n2 = 0; n2 < 32; ++n2) s += hl[n2][t];
    atomicAdd(&T[t], s);
  }
  __syncthreads();

  { // write V column-major bf16: lanes sweep nodes -> coalesced
    const int n = t & 31, q = t >> 5;  // 8 groups x 72 cols = 576
    for (int cc = 0; cc < 72; ++cc) {
      int col = q * 72 + cc;
      float val;
      if (col < 512) {
        int hh = col >> 7, rem = col & 127, d = rem & 63;
        float hv = hl[n][hh * 64 + d];
        val = (rem < 64) ? sdste[hh][n] * hv : hv;
      } else if (col < 516) val = sdste[col - 512][n];
      else if (col == 516)  val = 1.0f;
      else                  val = 0.0f;
      Vcm[(size_t)col * NN + nb + n] = f2bf(val);
    }
  }
}

// ---------------- Kernel 2: out2[ks] = adj(0/1 as bf16) @ V  (MFMA) ----------------
// tile 128x192, BK=64, grid = cb(3) x nks x rb(48), bid ordered for L2 B-residency.
// 4 waves 2x2, wave tile 64x96 (mt 4 x nt 6). LDS 40 KB, XOR-swizzled A and B.
__global__ __launch_bounds__(256, 3) void k2_gemm(
    const int* __restrict__ adj, const unsigned short* __restrict__ Vcm,
    float* __restrict__ out2, int nks)
{
  __shared__ unsigned short lA[128 * 64];  // 128 rows x 64k, XOR-swizzled granules
  __shared__ unsigned short lB[192 * 64];  // 192 cols x 64k, XOR-swizzled granules
  const int t   = threadIdx.x;
  const int bid = blockIdx.x;
  const int rb  = bid % 48;
  const int tmp = bid / 48;
  const int ks  = tmp % nks;
  const int cb  = tmp / nks;
  const int krange = NN / nks;
  const int i0 = rb * 128, n0 = cb * 192, k0 = ks * krange;
  const int w = t >> 6, l = t & 63;
  const int wm = w & 1, wn = w >> 1;
  const int lm = l & 15, lk = l >> 4;
  const int r  = t >> 1, cq = t & 1;       // A staging: row, 32-int half

  f32x4 acc[4][6];
#pragma unroll
  for (int mt = 0; mt < 4; ++mt)
#pragma unroll
    for (int nt = 0; nt < 6; ++nt) acc[mt][nt] = (f32x4){0.f, 0.f, 0.f, 0.f};

  const int iters = krange / 64;
  for (int it = 0; it < iters; ++it) {
    const int kb = k0 + it * 64;
    { // A: 128x64 int32 -> bf16 0/1 into LDS (swizzled granules, conflict-free)
      const int4* ap = (const int4*)(adj + (size_t)(i0 + r) * NN + kb + cq * 32);
#pragma unroll
      for (int g = 0; g < 4; ++g) {
        int4 qa = ap[2 * g], qb = ap[2 * g + 1];
        uint4 p;
        p.x = (unsigned)qa.x * 0x3F80u | (unsigned)qa.y * 0x3F800000u;
        p.y = (unsigned)qa.z * 0x3F80u | (unsigned)qa.w * 0x3F800000u;
        p.z = (unsigned)qb.x * 0x3F80u | (unsigned)qb.y * 0x3F800000u;
        p.w = (unsigned)qb.z * 0x3F80u | (unsigned)qb.w * 0x3F800000u;
        const int gran = cq * 4 + g;
        *(uint4*)(&lA[r * 64 + ((gran ^ (r & 7)) * 8)]) = p;
      }
    }
    { // B: async global->LDS, 16B/lane, XOR-swizzled granules
      const int clbase = w * 48;
      const int crow = l >> 3, j = l & 7;
#pragma unroll
      for (int u = 0; u < 6; ++u) {
        int cl = clbase + u * 8 + crow;
        int g = j ^ (cl & 7);
        const unsigned short* gp = Vcm + (size_t)(n0 + cl) * NN + kb + g * 8;
        async_load16(gp, (char*)lB + (size_t)(clbase + u * 8) * 128);
      }
    }
    __syncthreads();
#pragma unroll
    for (int ks2 = 0; ks2 < 2; ++ks2) {
      const int kgo = ks2 * 4 + lk;
      bf16x8 afrag[4];
#pragma unroll
      for (int mt = 0; mt < 4; ++mt) {
        const int rr = wm * 64 + mt * 16 + lm;
        afrag[mt] = *(const bf16x8*)(&lA[rr * 64 + ((kgo ^ (rr & 7)) * 8)]);
      }
      const int slot = (kgo ^ (lm & 7)) * 8;
#pragma unroll
      for (int nt = 0; nt < 6; ++nt) {
        bf16x8 b = *(const bf16x8*)(&lB[(wn * 96 + nt * 16 + lm) * 64 + slot]);
#pragma unroll
        for (int mt = 0; mt < 4; ++mt)
          acc[mt][nt] = __builtin_amdgcn_mfma_f32_16x16x32_bf16(afrag[mt], b, acc[mt][nt], 0, 0, 0);
      }
    }
    __syncthreads();
  }

  float* o = out2 + (size_t)ks * ((size_t)NN * NC);
  const int row0 = i0 + wm * 64 + (l >> 4) * 4;
  const int colb = n0 + wn * 96 + (l & 15);
#pragma unroll
  for (int mt = 0; mt < 4; ++mt)
#pragma unroll
    for (int nt = 0; nt < 6; ++nt)
#pragma unroll
      for (int rr = 0; rr < 4; ++rr)
        o[(size_t)(row0 + mt * 16 + rr) * NC + colb + nt * 16] = acc[mt][nt][rr];
}

// ---------------- Kernel 3: combine across nks K-partials ----------------
__global__ __launch_bounds__(256) void k3_final(
    const float* __restrict__ out2, const float* __restrict__ e_src,
    const float* __restrict__ T, float* __restrict__ out, int nks)
{
  const int n = blockIdx.x, c = threadIdx.x;
  const int h = c >> 6, d = c & 63;
  float Se = 0.f, Sp = 0.f, E = 0.f, dg = 0.f;
  for (int s = 0; s < nks; ++s) {
    const float* ra = out2 + (size_t)s * ((size_t)NN * NC) + (size_t)n * NC;
    Se += ra[h * 128 + d];
    Sp += ra[h * 128 + 64 + d];
    E  += ra[512 + h];
    dg += ra[516];
  }
  float e = e_src[h * NN + n];
  float D = e * E + ((float)NN - dg);
  out[(size_t)n * 256 + c] = (e * Se + (T[c] - Sp)) / D;
}

extern "C" void kernel_launch(void* const* d_in, const int* in_sizes, int n_in,
                              void* d_out, int out_size, void* d_ws, size_t ws_size,
                              hipStream_t stream) {
  const float* x  = (const float*)d_in[0];
  const int*   adj= (const int*)d_in[1];
  const float* W  = (const float*)d_in[2];
  const float* Wb = (const float*)d_in[3];
  const float* Aw = (const float*)d_in[4];
  const float* Ab = (const float*)d_in[5];
  float* out = (float*)d_out;
  char* ws = (char*)d_ws;
  unsigned short* Vcm = (unsigned short*)ws;            // 7,077,888 B
  float* e_src = (float*)(ws + 7077888);                // 98,304 B
  float* T     = (float*)(ws + 7176192);                // 1,024 B
  float* out2  = (float*)(ws + 7177216);                // nks x 6144 x 576 f32

  // K-split: prefer 4 (grid 576 = 2.25 blk/CU); fall back to 2 if ws is small.
  const size_t slab = (size_t)NN * NC * 4;
  int nks = (ws_size >= 7177216 + 4 * slab) ? 4 : 2;

  hipMemsetAsync(T, 0, 1024, stream);
  hipLaunchKernelGGL(k1_feat, dim3(192), dim3(256), 0, stream, x, W, Wb, Aw, Ab, Vcm, e_src, T);
  hipLaunchKernelGGL(k2_gemm, dim3(48 * 3 * nks), dim3(256), 0, stream, adj, Vcm, out2, nks);
  hipLaunchKernelGGL(k3_final, dim3(NN), dim3(256), 0, stream, out2, e_src, T, out, nks);
}

// Round 3
// 341.712 us; speedup vs baseline: 1.0696x; 1.0533x over previous
//
#include <hip/hip_runtime.h>
#include <stdint.h>

#define NN 6144        // nodes
#define NC 576         // padded V columns (517 used)

typedef __bf16 bf16x8 __attribute__((ext_vector_type(8)));
typedef float  f32x4  __attribute__((ext_vector_type(4)));

__device__ __forceinline__ unsigned short f2bf(float f) {
  unsigned u = __float_as_uint(f);
  u += 0x7FFFu + ((u >> 16) & 1u);   // RNE
  return (unsigned short)(u >> 16);
}

__device__ __forceinline__ void async_load16(const void* g, void* l) {
  __builtin_amdgcn_global_load_lds(
      (__attribute__((address_space(1))) void*)(uintptr_t)g,
      (__attribute__((address_space(3))) void*)(uint32_t)(uintptr_t)l,
      16, 0, 0);
}

// ---------------- Kernel 0: adj int32 -> bf16 (0/1) prepass; also zero T ----------------
__global__ __launch_bounds__(256) void k0_pack(
    const int* __restrict__ adj, unsigned short* __restrict__ Abf,
    float* __restrict__ T)
{
  if (blockIdx.x == 0 && threadIdx.x < 256) T[threadIdx.x] = 0.f;
  const size_t total8 = (size_t)NN * NN / 8;   // groups of 8 ints -> one uint4 out
  const int4* a4 = (const int4*)adj;
  uint4* o4 = (uint4*)Abf;
  for (size_t g = (size_t)blockIdx.x * 256 + threadIdx.x; g < total8;
       g += (size_t)gridDim.x * 256) {
    int4 qa = a4[2 * g], qb = a4[2 * g + 1];
    uint4 p;
    p.x = (unsigned)qa.x * 0x3F80u | (unsigned)qa.y * 0x3F800000u;
    p.y = (unsigned)qa.z * 0x3F80u | (unsigned)qa.w * 0x3F800000u;
    p.z = (unsigned)qb.x * 0x3F80u | (unsigned)qb.y * 0x3F800000u;
    p.w = (unsigned)qb.z * 0x3F80u | (unsigned)qb.w * 0x3F800000u;
    o4[g] = p;
  }
}

// ---------------- Kernel 1: features, score exponentials, V (bf16 col-major), T ----------------
// grid 192 x 256 thr; block handles 32 nodes. (unchanged — passed R1/R2)
__global__ __launch_bounds__(256) void k1_feat(
    const float* __restrict__ x, const float* __restrict__ W,
    const float* __restrict__ Wb, const float* __restrict__ Aw,
    const float* __restrict__ Ab, unsigned short* __restrict__ Vcm,
    float* __restrict__ e_src, float* __restrict__ T)
{
  __shared__ float xs[256][32];
  __shared__ float hl[32][257];
  __shared__ float sdste[4][32];
  const int t  = threadIdx.x;
  const int nb = blockIdx.x * 32;

  {
    const int n = t >> 3, kq = (t & 7) * 32;
    const float4* xp = (const float4*)(x + (size_t)(nb + n) * 256 + kq);
#pragma unroll
    for (int j = 0; j < 8; ++j) {
      float4 v = xp[j];
      int k = kq + j * 4;
      xs[k][n] = v.x; xs[k+1][n] = v.y; xs[k+2][n] = v.z; xs[k+3][n] = v.w;
    }
  }
  __syncthreads();

  const int cg = t & 31, ng = t >> 5;
  const int c0 = cg * 8, h = c0 >> 6, d0 = c0 & 63;
  const float* wp = W + h * 16384 + d0;
  float acc[4][8];
#pragma unroll
  for (int i = 0; i < 4; ++i)
#pragma unroll
    for (int j = 0; j < 8; ++j) acc[i][j] = 0.f;

#pragma unroll 4
  for (int k = 0; k < 256; ++k) {
    float4 wa = *(const float4*)(wp + (size_t)k * 64);
    float4 wb = *(const float4*)(wp + (size_t)k * 64 + 4);
    float4 xa = *(const float4*)(&xs[k][ng * 4]);
    float xr[4] = {xa.x, xa.y, xa.z, xa.w};
    float wr[8] = {wa.x, wa.y, wa.z, wa.w, wb.x, wb.y, wb.z, wb.w};
#pragma unroll
    for (int i = 0; i < 4; ++i)
#pragma unroll
      for (int j = 0; j < 8; ++j) acc[i][j] += xr[i] * wr[j];
  }
#pragma unroll
  for (int i = 0; i < 4; ++i)
#pragma unroll
    for (int j = 0; j < 8; ++j)
      hl[ng * 4 + i][c0 + j] = acc[i][j] + Wb[c0 + j];
  __syncthreads();

  if (t < 128) {
    const int node = t & 31, hd = t >> 5;
    float ss = Ab[hd], sd = 0.f;
#pragma unroll 8
    for (int d = 0; d < 64; ++d) {
      float hv = hl[node][hd * 64 + d];
      ss += hv * Aw[hd * 128 + d];
      sd += hv * Aw[hd * 128 + 64 + d];
    }
    e_src[hd * NN + nb + node] = expf(ss);
    sdste[hd][node] = expf(sd);
  }
  {
    float s = 0.f;
#pragma unroll 8
    for (int n2 = 0; n2 < 32; ++n2) s += hl[n2][t];
    atomicAdd(&T[t], s);
  }
  __syncthreads();

  {
    const int n = t & 31, q = t >> 5;
    for (int cc = 0; cc < 72; ++cc) {
      int col = q * 72 + cc;
      float val;
      if (col < 512) {
        int hh = col >> 7, rem = col & 127, d = rem & 63;
        float hv = hl[n][hh * 64 + d];
        val = (rem < 64) ? sdste[hh][n] * hv : hv;
      } else if (col < 516) val = sdste[col - 512][n];
      else if (col == 516)  val = 1.0f;
      else                  val = 0.0f;
      Vcm[(size_t)col * NN + nb + n] = f2bf(val);
    }
  }
}

// ---------------- Kernel 2: out2[ks] = Abf @ V, pure-async staging (m97 structure) ----------------
// tile 96x192, BK=64, grid = cb(3) x ks(nks) x rb(64) -> 768 blocks @ nks=4 = 3 blocks/CU.
// 4 waves 2x2, wave tile 48x96 (mt3 x nt6). LDS 36 KB, XOR-swizzled granules both operands.
__global__ __launch_bounds__(256, 3) void k2_gemm(
    const unsigned short* __restrict__ Abf, const unsigned short* __restrict__ Vcm,
    float* __restrict__ out2, int nks)
{
  __shared__ unsigned short lA[96 * 64];   // 96 rows x 64k
  __shared__ unsigned short lB[192 * 64];  // 192 cols x 64k
  const int t   = threadIdx.x;
  const int bid = blockIdx.x;
  const int rb  = bid & 63;
  const int tmp = bid >> 6;
  const int ks  = tmp % nks;
  const int cb  = tmp / nks;
  const int krange = NN / nks;
  const int i0 = rb * 96, n0 = cb * 192, k0 = ks * krange;
  const int w = t >> 6, l = t & 63;
  const int wm = w & 1, wn = w >> 1;
  const int lm = l & 15, lk = l >> 4;

  f32x4 acc[3][6];
#pragma unroll
  for (int mt = 0; mt < 3; ++mt)
#pragma unroll
    for (int nt = 0; nt < 6; ++nt) acc[mt][nt] = (f32x4){0.f, 0.f, 0.f, 0.f};

  const int iters = krange / 64;
  for (int it = 0; it < iters; ++it) {
    const int kb = k0 + it * 64;
    { // A: 96x64 bf16, 768 granules, 3 issues/thread
#pragma unroll
      for (int u = 0; u < 3; ++u) {
        const int gi0 = w * 192 + u * 64;
        const int gi  = gi0 + l;
        const int row = gi >> 3, gsl = gi & 7;
        const int gsrc = gsl ^ (row & 7);
        async_load16(Abf + (size_t)(i0 + row) * NN + kb + gsrc * 8,
                     (char*)lA + (size_t)gi0 * 16);
      }
    }
    { // B: 192x64 bf16, 1536 granules, 6 issues/thread
#pragma unroll
      for (int u = 0; u < 6; ++u) {
        const int gi0 = w * 384 + u * 64;
        const int gi  = gi0 + l;
        const int col = gi >> 3, gsl = gi & 7;
        const int gsrc = gsl ^ (col & 7);
        async_load16(Vcm + (size_t)(n0 + col) * NN + kb + gsrc * 8,
                     (char*)lB + (size_t)gi0 * 16);
      }
    }
    __syncthreads();
#pragma unroll
    for (int ks2 = 0; ks2 < 2; ++ks2) {
      const int kgo = ks2 * 4 + lk;
      bf16x8 afrag[3];
#pragma unroll
      for (int mt = 0; mt < 3; ++mt) {
        const int rr = wm * 48 + mt * 16 + lm;
        afrag[mt] = *(const bf16x8*)((const char*)lA + (size_t)rr * 128 + ((kgo ^ (rr & 7)) * 16));
      }
#pragma unroll
      for (int nt = 0; nt < 6; ++nt) {
        const int cc = wn * 96 + nt * 16 + lm;
        bf16x8 b = *(const bf16x8*)((const char*)lB + (size_t)cc * 128 + ((kgo ^ (cc & 7)) * 16));
#pragma unroll
        for (int mt = 0; mt < 3; ++mt)
          acc[mt][nt] = __builtin_amdgcn_mfma_f32_16x16x32_bf16(afrag[mt], b, acc[mt][nt], 0, 0, 0);
      }
    }
    __syncthreads();
  }

  float* o = out2 + (size_t)ks * ((size_t)NN * NC);
  const int row0 = i0 + wm * 48 + (l >> 4) * 4;
  const int colb = n0 + wn * 96 + (l & 15);
#pragma unroll
  for (int mt = 0; mt < 3; ++mt)
#pragma unroll
    for (int nt = 0; nt < 6; ++nt)
#pragma unroll
      for (int rr = 0; rr < 4; ++rr)
        o[(size_t)(row0 + mt * 16 + rr) * NC + colb + nt * 16] = acc[mt][nt][rr];
}

// ---------------- Kernel 2 legacy (in-kernel convert, for small ws) ----------------
__global__ __launch_bounds__(256, 3) void k2_legacy(
    const int* __restrict__ adj, const unsigned short* __restrict__ Vcm,
    float* __restrict__ out2, int nks)
{
  __shared__ unsigned short lA[128 * 64];
  __shared__ unsigned short lB[192 * 64];
  const int t   = threadIdx.x;
  const int bid = blockIdx.x;
  const int rb  = bid % 48;
  const int tmp = bid / 48;
  const int ks  = tmp % nks;
  const int cb  = tmp / nks;
  const int krange = NN / nks;
  const int i0 = rb * 128, n0 = cb * 192, k0 = ks * krange;
  const int w = t >> 6, l = t & 63;
  const int wm = w & 1, wn = w >> 1;
  const int lm = l & 15, lk = l >> 4;
  const int r  = t >> 1, cq = t & 1;

  f32x4 acc[4][6];
#pragma unroll
  for (int mt = 0; mt < 4; ++mt)
#pragma unroll
    for (int nt = 0; nt < 6; ++nt) acc[mt][nt] = (f32x4){0.f, 0.f, 0.f, 0.f};

  const int iters = krange / 64;
  for (int it = 0; it < iters; ++it) {
    const int kb = k0 + it * 64;
    {
      const int4* ap = (const int4*)(adj + (size_t)(i0 + r) * NN + kb + cq * 32);
#pragma unroll
      for (int g = 0; g < 4; ++g) {
        int4 qa = ap[2 * g], qb = ap[2 * g + 1];
        uint4 p;
        p.x = (unsigned)qa.x * 0x3F80u | (unsigned)qa.y * 0x3F800000u;
        p.y = (unsigned)qa.z * 0x3F80u | (unsigned)qa.w * 0x3F800000u;
        p.z = (unsigned)qb.x * 0x3F80u | (unsigned)qb.y * 0x3F800000u;
        p.w = (unsigned)qb.z * 0x3F80u | (unsigned)qb.w * 0x3F800000u;
        const int gran = cq * 4 + g;
        *(uint4*)(&lA[r * 64 + ((gran ^ (r & 7)) * 8)]) = p;
      }
    }
    {
      const int clbase = w * 48;
      const int crow = l >> 3, j = l & 7;
#pragma unroll
      for (int u = 0; u < 6; ++u) {
        int cl = clbase + u * 8 + crow;
        int g = j ^ (cl & 7);
        async_load16(Vcm + (size_t)(n0 + cl) * NN + kb + g * 8,
                     (char*)lB + (size_t)(clbase + u * 8) * 128);
      }
    }
    __syncthreads();
#pragma unroll
    for (int ks2 = 0; ks2 < 2; ++ks2) {
      const int kgo = ks2 * 4 + lk;
      bf16x8 afrag[4];
#pragma unroll
      for (int mt = 0; mt < 4; ++mt) {
        const int rr = wm * 64 + mt * 16 + lm;
        afrag[mt] = *(const bf16x8*)(&lA[rr * 64 + ((kgo ^ (rr & 7)) * 8)]);
      }
#pragma unroll
      for (int nt = 0; nt < 6; ++nt) {
        bf16x8 b = *(const bf16x8*)(&lB[(wn * 96 + nt * 16 + lm) * 64 + ((kgo ^ (lm & 7)) * 8)]);
#pragma unroll
        for (int mt = 0; mt < 4; ++mt)
          acc[mt][nt] = __builtin_amdgcn_mfma_f32_16x16x32_bf16(afrag[mt], b, acc[mt][nt], 0, 0, 0);
      }
    }
    __syncthreads();
  }

  float* o = out2 + (size_t)ks * ((size_t)NN * NC);
  const int row0 = i0 + wm * 64 + (l >> 4) * 4;
  const int colb = n0 + wn * 96 + (l & 15);
#pragma unroll
  for (int mt = 0; mt < 4; ++mt)
#pragma unroll
    for (int nt = 0; nt < 6; ++nt)
#pragma unroll
      for (int rr = 0; rr < 4; ++rr)
        o[(size_t)(row0 + mt * 16 + rr) * NC + colb + nt * 16] = acc[mt][nt][rr];
}

// ---------------- Kernel 3: combine across nks K-partials ----------------
__global__ __launch_bounds__(256) void k3_final(
    const float* __restrict__ out2, const float* __restrict__ e_src,
    const float* __restrict__ T, float* __restrict__ out, int nks)
{
  const int n = blockIdx.x, c = threadIdx.x;
  const int h = c >> 6, d = c & 63;
  float Se = 0.f, Sp = 0.f, E = 0.f, dg = 0.f;
  for (int s = 0; s < nks; ++s) {
    const float* ra = out2 + (size_t)s * ((size_t)NN * NC) + (size_t)n * NC;
    Se += ra[h * 128 + d];
    Sp += ra[h * 128 + 64 + d];
    E  += ra[512 + h];
    dg += ra[516];
  }
  float e = e_src[h * NN + n];
  float D = e * E + ((float)NN - dg);
  out[(size_t)n * 256 + c] = (e * Se + (T[c] - Sp)) / D;
}

extern "C" void kernel_launch(void* const* d_in, const int* in_sizes, int n_in,
                              void* d_out, int out_size, void* d_ws, size_t ws_size,
                              hipStream_t stream) {
  const float* x  = (const float*)d_in[0];
  const int*   adj= (const int*)d_in[1];
  const float* W  = (const float*)d_in[2];
  const float* Wb = (const float*)d_in[3];
  const float* Aw = (const float*)d_in[4];
  const float* Ab = (const float*)d_in[5];
  float* out = (float*)d_out;
  char* ws = (char*)d_ws;
  unsigned short* Vcm = (unsigned short*)ws;            // 7,077,888 B
  float* e_src = (float*)(ws + 7077888);                // 98,304 B
  float* T     = (float*)(ws + 7176192);                // 1,024 B
  unsigned short* Abf = (unsigned short*)(ws + 7177216);// 75,497,472 B
  float* out2A = (float*)(ws + 82674688);               // nks x 14,155,776 B (async path)
  float* out2L = (float*)(ws + 7177216);                // legacy path overlays Abf

  const size_t slab = (size_t)NN * NC * 4;

  if (ws_size >= 82674688 + 2 * slab) {
    // Async (m97-structure) path: prepass converts adj -> bf16.
    int nks = (ws_size >= 82674688 + 4 * slab) ? 4 : 2;
    hipLaunchKernelGGL(k0_pack, dim3(2048), dim3(256), 0, stream, adj, Abf, T);
    hipLaunchKernelGGL(k1_feat, dim3(192), dim3(256), 0, stream, x, W, Wb, Aw, Ab, Vcm, e_src, T);
    hipLaunchKernelGGL(k2_gemm, dim3(64 * 3 * nks), dim3(256), 0, stream, Abf, Vcm, out2A, nks);
    hipLaunchKernelGGL(k3_final, dim3(NN), dim3(256), 0, stream, out2A, e_src, T, out, nks);
  } else {
    int nks = (ws_size >= 7177216 + 4 * slab) ? 4 : 2;
    hipMemsetAsync(T, 0, 1024, stream);
    hipLaunchKernelGGL(k1_feat, dim3(192), dim3(256), 0, stream, x, W, Wb, Aw, Ab, Vcm, e_src, T);
    hipLaunchKernelGGL(k2_legacy, dim3(48 * 3 * nks), dim3(256), 0, stream, adj, Vcm, out2L, nks);
    hipLaunchKernelGGL(k3_final, dim3(NN), dim3(256), 0, stream, out2L, e_src, T, out, nks);
  }
}